// Round 2
// baseline (420.075 us; speedup 1.0000x reference)
//
#include <hip/hip_runtime.h>

typedef _Float16 half_t;
typedef __attribute__((ext_vector_type(8))) _Float16 half8;
typedef __attribute__((ext_vector_type(4))) _Float16 half4;
typedef __attribute__((ext_vector_type(4))) float f32x4;

#define B_ 4
#define N_ 4096
#define D_ 1024
#define R_ (B_ * N_) // 16384

// ---------------------------------------------------------------------------
// async global->LDS, 16B per lane. LDS dest must be wave-uniform base + lane*16.
__device__ __forceinline__ void gload_lds16(const half_t* g, half_t* l) {
    __builtin_amdgcn_global_load_lds(
        (const __attribute__((address_space(1))) unsigned int*)g,
        (__attribute__((address_space(3))) unsigned int*)l, 16, 0, 0);
}

// raw workgroup barrier: NO vmcnt/lgkmcnt drain. Cross-wave visibility of
// global_load_lds writes is carried by the explicit counted vmcnt before it.
__device__ __forceinline__ void wgbar() {
    asm volatile("" ::: "memory");
    __builtin_amdgcn_s_barrier();
    asm volatile("" ::: "memory");
}

// ---------------------------------------------------------------------------
// C[m,n] = sum_k A[m,k] * Bt[n,k]   (A row-major [M,K], B given transposed [N,K])
// 256x256 tile, 512 threads (8 waves = 2M x 4N, each 128x64 output).
// FREE-RUN schedule: BK=32, FOUR independent LDS buffers (128 KiB total).
// Per 32-K tile: { issue stage(kt+2) -> buf (kt+2)&3 ; 12x ds_read_b128 ;
//                  32x MFMA (setprio-wrapped) ; vmcnt(4) ; barrier }
// ONE barrier per tile (vs 8 per 64K in the phase-locked version): staging
// never writes a live buffer (reuse distance 4 tiles = >=2 barriers after its
// readers' MFMAs consumed the data), so waves de-lockstep inside the tile and
// one wave's MFMA overlaps another wave's LDS reads. Counted vmcnt(4) keeps
// 2 tiles (8 loads) in flight; issued ~2 tile-times (~2800 cyc) before their
// wait -> HBM latency fully covered; never drained to 0 in steady state.
// LDS block [256 rows][32 k] halfs, 16B chunks XOR-swizzled:
//   phys_chunk(row,q) = row*4 + (q ^ ((row>>1)&3))
// applied on BOTH sides (pre-swizzled global source + swizzled ds_read).
// EPI: 0 = fp32 C, 1 = f16 C, 2 = fp32 C + bias (bias indexed by column)
// ZSHIFT: blockIdx.z = (batch << ZSHIFT) | ksplit; k window = ksplit*K .. +K.
// Requires: K % 32 == 0, nk = K/32 >= 2.
template <int EPI, int ZSHIFT, int SWAP>
__global__ __launch_bounds__(512, 2) void gemm256(
    const half_t* __restrict__ A, const half_t* __restrict__ Bt,
    void* __restrict__ Cv, const float* __restrict__ bias,
    int lda, int ldb, int ldc, int K,
    long sA, long sB, long sC, float scale)
{
    __shared__ __align__(16) half_t As[4][256 * 32]; // [buf][row*32+chunk]
    __shared__ __align__(16) half_t Bs[4][256 * 32];

    const int t = threadIdx.x;
    const int wave = t >> 6;
    const int lane = t & 63;
    const int l15 = lane & 15;
    const int q = lane >> 4;
    const int wm = wave >> 2;  // 0..1 (M)
    const int wn = wave & 3;   // 0..3 (N)
    const int m0 = (SWAP ? blockIdx.x : blockIdx.y) * 256;
    const int n0 = (SWAP ? blockIdx.y : blockIdx.x) * 256;
    const long zb = blockIdx.z >> ZSHIFT;
    const int zs = blockIdx.z & ((1 << ZSHIFT) - 1);

    // staging: physical chunk c (16B) holds logical (row = c>>2, chunk = (c&3)^((c>>3)&3))
    const int c0 = t, c1 = t + 512;
    const int r0 = c0 >> 2, r1 = c1 >> 2;
    const int g0 = ((c0 & 3) ^ ((c0 >> 3) & 3)) * 8; // halfs
    const int g1 = ((c1 & 3) ^ ((c1 >> 3) & 3)) * 8;

    const half_t* Ab = A + zb * sA + (long)m0 * lda + zs * K;
    const half_t* Bb = Bt + zb * sB + (long)n0 * ldb + zs * K;
    const long a0 = (long)r0 * lda + g0, a1 = (long)r1 * lda + g1;
    const long b0 = (long)r0 * ldb + g0, b1 = (long)r1 * ldb + g1;

    // fragment ds_read: row bits 1..2 come from l15 (bases are 16-aligned)
    const int qq = (q ^ ((l15 >> 1) & 3)) * 8; // halfs

    f32x4 acc[8][4] = {};
    const int nk = K >> 5;

#define STAGE(kt) do { const int kb_ = (kt) * 32; const int bf_ = (kt) & 3; \
        gload_lds16(Ab + a0 + kb_, &As[bf_][c0 * 8]);                       \
        gload_lds16(Ab + a1 + kb_, &As[bf_][c1 * 8]);                       \
        gload_lds16(Bb + b0 + kb_, &Bs[bf_][c0 * 8]);                       \
        gload_lds16(Bb + b1 + kb_, &Bs[bf_][c1 * 8]); } while (0)

    // prologue: tiles 0 and 1 in flight; wait tile 0 (leave tile 1 pending)
    STAGE(0); STAGE(1);
    asm volatile("s_waitcnt vmcnt(4)" ::: "memory");
    wgbar();

    for (int kt = 0; kt < nk; ++kt) {
        const int cb = kt & 3;
        if (kt + 2 < nk) STAGE(kt + 2);
        half8 bf[4], af[8];
#pragma unroll
        for (int j = 0; j < 4; j++)
            bf[j] = *(const half8*)&Bs[cb][(wn * 64 + j * 16 + l15) * 32 + qq];
#pragma unroll
        for (int i = 0; i < 8; i++)
            af[i] = *(const half8*)&As[cb][(wm * 128 + i * 16 + l15) * 32 + qq];
        __builtin_amdgcn_s_setprio(1);
#pragma unroll
        for (int i = 0; i < 8; i++)
#pragma unroll
            for (int j = 0; j < 4; j++)
                acc[i][j] = __builtin_amdgcn_mfma_f32_16x16x32_f16(af[i], bf[j], acc[i][j], 0, 0, 0);
        __builtin_amdgcn_s_setprio(0);
        // tile kt+1 must be resident before next iteration's reads
        if (kt + 2 < nk)      asm volatile("s_waitcnt vmcnt(4)" ::: "memory");
        else if (kt + 1 < nk) asm volatile("s_waitcnt vmcnt(0)" ::: "memory");
        if (kt + 1 < nk) wgbar();
    }
#undef STAGE

    // epilogue: acc[i][j] -> row = wm*128 + i*16 + q*4 + r, col = wn*64 + j*16 + l15
    if (EPI == 1) {
        half_t* C = (half_t*)Cv + (long)blockIdx.z * sC + (long)m0 * ldc + n0;
#pragma unroll
        for (int i = 0; i < 8; i++) {
            const int rowb = wm * 128 + i * 16 + q * 4;
#pragma unroll
            for (int j = 0; j < 4; j++) {
                const int col = wn * 64 + j * 16 + l15;
#pragma unroll
                for (int r = 0; r < 4; r++)
                    C[(long)(rowb + r) * ldc + col] = (half_t)(acc[i][j][r] * scale);
            }
        }
    } else {
        float* C = (float*)Cv + (long)blockIdx.z * sC + (long)m0 * ldc + n0;
#pragma unroll
        for (int i = 0; i < 8; i++) {
            const int rowb = wm * 128 + i * 16 + q * 4;
#pragma unroll
            for (int j = 0; j < 4; j++) {
                const int col = wn * 64 + j * 16 + l15;
                const float bv = (EPI == 2) ? bias[n0 + col] : 0.0f;
#pragma unroll
                for (int r = 0; r < 4; r++)
                    C[(long)(rowb + r) * ldc + col] = acc[i][j][r] * scale + bv;
            }
        }
    }
}

// ---------------------------------------------------------------------------
// sum 4 split-K f16 partials (fp32 math) -> f16. P laid [z = b*4+s][1M halfs].
__global__ __launch_bounds__(256) void ctx_reduce_h(
    const half_t* __restrict__ P, half_t* __restrict__ ctx)
{
    const long i = ((long)blockIdx.x * 256 + threadIdx.x) * 8;
    const long b = i >> 20;
    const long idx = i & ((1L << 20) - 1);
    const half_t* p = P + (b * 4) * (1L << 20) + idx;
    const half8 s0 = *(const half8*)(p);
    const half8 s1 = *(const half8*)(p + (1L << 20));
    const half8 s2 = *(const half8*)(p + 2 * (1L << 20));
    const half8 s3 = *(const half8*)(p + 3 * (1L << 20));
    half8 o;
#pragma unroll
    for (int j = 0; j < 8; j++)
        o[j] = (half_t)((float)s0[j] + (float)s1[j] + (float)s2[j] + (float)s3[j]);
    *(half8*)(ctx + i) = o;
}

// ---------------------------------------------------------------------------
// fp32 -> f16 elementwise (8 elems/thread)
__global__ __launch_bounds__(256) void convert_f32_f16(
    const float* __restrict__ in, half_t* __restrict__ out)
{
    const long i = ((long)blockIdx.x * 256 + threadIdx.x) * 8;
    const float4 a = *(const float4*)(in + i);
    const float4 b = *(const float4*)(in + i + 4);
    half8 o = {(half_t)a.x, (half_t)a.y, (half_t)a.z, (half_t)a.w,
               (half_t)b.x, (half_t)b.y, (half_t)b.z, (half_t)b.w};
    *(half8*)(out + i) = o;
}

// ---------------------------------------------------------------------------
// four 1024x1024 fp32 -> f16 transposed in one launch (z selects matrix)
__global__ void transpose_w4(const float* __restrict__ W0, const float* __restrict__ W1,
                             const float* __restrict__ W2, const float* __restrict__ W3,
                             half_t* __restrict__ Wt)
{
    __shared__ float tile[32][33];
    const float* W = blockIdx.z == 0 ? W0 : blockIdx.z == 1 ? W1
                   : blockIdx.z == 2 ? W2 : W3;
    half_t* dst = Wt + (size_t)blockIdx.z * 1024 * 1024;
    const int tx = threadIdx.x, ty = threadIdx.y;
    const int bx = blockIdx.x * 32, by = blockIdx.y * 32;
#pragma unroll
    for (int yy = ty; yy < 32; yy += 8)
        tile[yy][tx] = W[(long)(by + yy) * 1024 + bx + tx];
    __syncthreads();
#pragma unroll
    for (int yy = ty; yy < 32; yy += 8)
        dst[(long)(bx + yy) * 1024 + by + tx] = (half_t)tile[tx][yy];
}

// ---------------------------------------------------------------------------
// row softmax over 1024 features (f16 in, fp32 math); one block per row.
// Output scaled by 64 (f16 subnormal guard; compensated in final epilogue).
__global__ __launch_bounds__(256) void softmax_rows(
    const half_t* __restrict__ L, half_t* __restrict__ Qh)
{
    const int r = blockIdx.x;
    const int t = threadIdx.x;
    const half4 xh = ((const half4*)(L + (long)r * 1024))[t];
    const float x0 = (float)xh[0], x1 = (float)xh[1],
                x2 = (float)xh[2], x3 = (float)xh[3];
    float m = fmaxf(fmaxf(x0, x1), fmaxf(x2, x3));
#pragma unroll
    for (int o = 32; o > 0; o >>= 1) m = fmaxf(m, __shfl_xor(m, o, 64));
    __shared__ float redm[4], reds[4];
    const int wave = t >> 6;
    if ((t & 63) == 0) redm[wave] = m;
    __syncthreads();
    m = fmaxf(fmaxf(redm[0], redm[1]), fmaxf(redm[2], redm[3]));
    const float e0 = __expf(x0 - m), e1 = __expf(x1 - m),
                e2 = __expf(x2 - m), e3 = __expf(x3 - m);
    float s = e0 + e1 + e2 + e3;
#pragma unroll
    for (int o = 32; o > 0; o >>= 1) s += __shfl_xor(s, o, 64);
    if ((t & 63) == 0) reds[wave] = s;
    __syncthreads();
    s = reds[0] + reds[1] + reds[2] + reds[3];
    const float rs = 64.0f / s;
    half4 o4 = {(half_t)(e0 * rs), (half_t)(e1 * rs),
                (half_t)(e2 * rs), (half_t)(e3 * rs)};
    ((half4*)(Qh + (long)r * 1024))[t] = o4;
}

// ---------------------------------------------------------------------------
// row softmax over 4096 (sequence softmax in transposed layout); input rows
// live inside the merged KV-logit tensor [B][2048][4096] (K part = rows
// 0..1023 of each batch slab). One block per (b,d) row, 16 elems/thread.
// Output scaled by 64 into Kt [B][D][N].
__global__ __launch_bounds__(256) void softmax_seq(
    const half_t* __restrict__ KV, half_t* __restrict__ O)
{
    const long r = blockIdx.x;              // 0 .. B*D-1
    const long b = r >> 10;
    const long d = r & 1023;
    const int t = threadIdx.x;
    const half_t* row = KV + (b * 2048 + d) * 4096;
    const half8 h0 = *(const half8*)(row + t * 16);
    const half8 h1 = *(const half8*)(row + t * 16 + 8);
    float v[16];
#pragma unroll
    for (int j = 0; j < 8; j++) { v[j] = (float)h0[j]; v[8 + j] = (float)h1[j]; }
    float m = v[0];
#pragma unroll
    for (int j = 1; j < 16; j++) m = fmaxf(m, v[j]);
#pragma unroll
    for (int o = 32; o > 0; o >>= 1) m = fmaxf(m, __shfl_xor(m, o, 64));
    __shared__ float redm[4], reds[4];
    const int wave = t >> 6;
    if ((t & 63) == 0) redm[wave] = m;
    __syncthreads();
    m = fmaxf(fmaxf(redm[0], redm[1]), fmaxf(redm[2], redm[3]));
    float s = 0.0f;
#pragma unroll
    for (int j = 0; j < 16; j++) { v[j] = __expf(v[j] - m); s += v[j]; }
#pragma unroll
    for (int o = 32; o > 0; o >>= 1) s += __shfl_xor(s, o, 64);
    if ((t & 63) == 0) reds[wave] = s;
    __syncthreads();
    s = reds[0] + reds[1] + reds[2] + reds[3];
    const float rs = 64.0f / s;
    half8 o0, o1;
#pragma unroll
    for (int j = 0; j < 8; j++) {
        o0[j] = (half_t)(v[j] * rs);
        o1[j] = (half_t)(v[8 + j] * rs);
    }
    *(half8*)(O + r * 4096 + t * 16) = o0;
    *(half8*)(O + r * 4096 + t * 16 + 8) = o1;
}

// ---------------------------------------------------------------------------
extern "C" void kernel_launch(void* const* d_in, const int* in_sizes, int n_in,
                              void* d_out, int out_size, void* d_ws, size_t ws_size,
                              hipStream_t stream)
{
    const float* x  = (const float*)d_in[0];
    const float* Wq = (const float*)d_in[1];
    const float* Wk = (const float*)d_in[2];
    const float* Wv = (const float*)d_in[3];
    const float* Wo = (const float*)d_in[4];
    const float* bo = (const float*)d_in[5];
    float* out = (float*)d_out;

    // Workspace (184 MiB):
    //   Xh 32 MiB (x as f16; dead after KV GEMM -> reused for split-K partials P)
    //   KVreg 64 MiB: first 32 MiB doubles as Q-logits (dead before KV GEMM
    //     writes); then merged KV logits [B][2048][4096] (K rows 0..1023,
    //     V rows 1024..2047 per batch slab).
    char* w = (char*)d_ws;
    half_t* Xh  = (half_t*)w;                                  // 32 MiB
    half_t* P   = (half_t*)w;                                  // 32 MiB (aliases Xh)
    w += (size_t)R_ * D_ * 2;
    half_t* KVreg = (half_t*)w;                                // 64 MiB
    half_t* Qlog  = KVreg;                                     // 32 MiB (pre-KV)
    w += (size_t)B_ * 2048 * 4096 * 2;
    half_t* Qh  = (half_t*)w; w += (size_t)R_ * D_ * 2;        // 32 MiB (q * 64)
    half_t* Kt  = (half_t*)w; w += (size_t)R_ * D_ * 2;        // 32 MiB [B,D,N] (k * 64)
    half_t* Wt  = (half_t*)w; w += (size_t)4 * D_ * D_ * 2;    // 8 MiB (Wq^T|Wk^T|Wv^T|Wo^T)
    half_t* ctx = (half_t*)w; w += (size_t)B_ * D_ * D_ * 2;   // 8 MiB (64 * K^T V)
    half_t* Mt  = (half_t*)w; w += (size_t)B_ * D_ * D_ * 2;   // 8 MiB (64 * (ctx Wo)^T)
    (void)ws_size; (void)in_sizes; (void)n_in; (void)out_size;

    const dim3 blk(256);
    const dim3 blkg(512);
    const long M1 = 1L << 20;

    convert_f32_f16<<<R_ * D_ / (256 * 8), blk, 0, stream>>>(x, Xh);
    transpose_w4<<<dim3(32, 32, 4), dim3(32, 8), 0, stream>>>(Wq, Wk, Wv, Wo, Wt);

    // ---- Q: Qlog[n,d] = Xh @ Wq (A big -> SWAP=1), then feature softmax
    gemm256<1, 0, 1><<<dim3(64, 4, 1), blkg, 0, stream>>>(Xh, Wt, Qlog, nullptr,
        1024, 1024, 1024, 1024, 0, 0, 0, 1.0f);
    softmax_rows<<<R_, blk, 0, stream>>>(Qlog, Qh);

    // ---- merged K|V transposed: KVreg[b][m][n] = sum_k Wkv^T[m,k] Xh[b][n,k]
    // (m = 0..1023 -> K logits, 1024..2047 -> V). Wk^T|Wv^T are contiguous in Wt.
    gemm256<1, 0, 0><<<dim3(16, 8, B_), blkg, 0, stream>>>(Wt + M1, Xh, KVreg, nullptr,
        1024, 1024, 4096, 1024, 0, (long)N_ * D_, (long)2048 * 4096, 1.0f);
    softmax_seq<<<B_ * D_, blk, 0, stream>>>(KVreg, Kt);

    // ---- ctx[b][d][e] = sum_n (64 k[n,d]) v[n,e], split-K=4, f16 partials
    // (Xh dead -> its region holds P). V = rows 1024.. of each KV slab.
    gemm256<1, 2, 1><<<dim3(4, 4, 16), blkg, 0, stream>>>(Kt, KVreg + (long)1024 * 4096, P, nullptr,
        N_, N_, 1024, N_ / 4,
        (long)D_ * N_, (long)2048 * 4096, M1, 1.0f);
    ctx_reduce_h<<<2048, blk, 0, stream>>>(P, ctx);

    // ---- Mt[b][e][d] = sum_f Wo[f][e] ctx[b][d][f], split-K=4 (A=Wo^T, Bt=ctx)
    gemm256<1, 2, 1><<<dim3(4, 4, 16), blkg, 0, stream>>>(Wt + 3 * M1, ctx, P, nullptr,
        1024, 1024, 1024, 256,
        0, M1, M1, 1.0f);
    ctx_reduce_h<<<2048, blk, 0, stream>>>(P, Mt);

    // ---- out[b][n][e] = (sum_d 64 q[n,d] * Mt[b][e][d]) * 2^-25 + bo[e]
    // 2^-25 = (1/8 head scale) * (1/1024 D_OUT) * (1/64 q) * (1/64 k), all exact
    gemm256<2, 0, 1><<<dim3(16, 4, B_), blkg, 0, stream>>>(Qh, Mt, out, bo,
        1024, 1024, 1024, 1024,
        (long)N_ * D_, M1, (long)N_ * D_,
        1.0f / 33554432.0f);
}

// Round 3
// 387.644 us; speedup vs baseline: 1.0837x; 1.0837x over previous
//
#include <hip/hip_runtime.h>

typedef _Float16 half_t;
typedef __attribute__((ext_vector_type(8))) _Float16 half8;
typedef __attribute__((ext_vector_type(4))) _Float16 half4;
typedef __attribute__((ext_vector_type(4))) float f32x4;

#define B_ 4
#define N_ 4096
#define D_ 1024
#define R_ (B_ * N_) // 16384

// ---------------------------------------------------------------------------
// async global->LDS, 16B per lane. LDS dest must be wave-uniform base + lane*16.
__device__ __forceinline__ void gload_lds16(const half_t* g, half_t* l) {
    __builtin_amdgcn_global_load_lds(
        (const __attribute__((address_space(1))) unsigned int*)g,
        (__attribute__((address_space(3))) unsigned int*)l, 16, 0, 0);
}

// raw workgroup barrier: NO vmcnt(0)/lgkmcnt(0) drain (that drain is the
// 2-phase ceiling). Memory clobbers pin compile-time order of LDS/global ops
// to their phase. Cross-wave visibility of global_load_lds writes is carried
// by the explicit counted vmcnt before the barrier.
__device__ __forceinline__ void wgbar() {
    asm volatile("" ::: "memory");
    __builtin_amdgcn_s_barrier();
    asm volatile("" ::: "memory");
}

// ---------------------------------------------------------------------------
// C[m,n] = sum_k A[m,k] * Bt[n,k]   (A row-major [M,K], B given transposed [N,K])
// 256x256 tile, BK=64, 512 threads (8 waves = 2M x 4N, each 128x64 output).
// 8-phase schedule (4 phases per K-tile, 2 K-tiles per LDS double-buffer pair):
//   phase = { ds-read frags | issue 1 half-tile global_load_lds } barrier
//           { setprio(1) 16x MFMA setprio(0) } barrier
// Counted vmcnt(6) once per K-tile (3 half-tiles in flight), drain only in tail.
// LDS per ks-block: [256 rows][32 k] halfs (64B rows), 16B chunks XOR-swizzled:
//   phys_chunk(row,q) = row*4 + (q ^ ((row>>1)&3))
// applied on BOTH sides: pre-swizzled global source (stage) + swizzled ds_read.
// EPI: 0 = fp32 C, 1 = f16 C, 2 = fp32 C + bias (bias indexed by column)
// ZSHIFT: blockIdx.z = (batch << ZSHIFT) | ksplit; k window = ksplit*K .. +K.
//         C offset uses full blockIdx.z (split-K partials laid out per z).
// Requires: K % 64 == 0, nk2 = K/64 >= 2.
template <int EPI, int ZSHIFT, int SWAP>
__global__ __launch_bounds__(512, 2) void gemm256(
    const half_t* __restrict__ A, const half_t* __restrict__ Bt,
    void* __restrict__ Cv, const float* __restrict__ bias,
    int lda, int ldb, int ldc, int K,
    long sA, long sB, long sC, float scale)
{
    __shared__ __align__(16) half_t As[2][2][256 * 32]; // [buf][ks][row*32+chunk]
    __shared__ __align__(16) half_t Bs[2][2][256 * 32];

    const int t = threadIdx.x;
    const int wave = t >> 6;
    const int lane = t & 63;
    const int l15 = lane & 15;
    const int q = lane >> 4;
    const int wm = wave >> 2;  // 0..1 (M)
    const int wn = wave & 3;   // 0..3 (N)
    const int m0 = (SWAP ? blockIdx.x : blockIdx.y) * 256;
    const int n0 = (SWAP ? blockIdx.y : blockIdx.x) * 256;
    const long zb = blockIdx.z >> ZSHIFT;
    const int zs = blockIdx.z & ((1 << ZSHIFT) - 1);

    // staging: physical chunk c (16B) holds logical (row = c>>2, chunk = (c&3)^((c>>3)&3))
    const int c0 = t, c1 = t + 512;
    const int r0 = c0 >> 2, r1 = c1 >> 2;
    const int g0 = ((c0 & 3) ^ ((c0 >> 3) & 3)) * 8; // halfs
    const int g1 = ((c1 & 3) ^ ((c1 >> 3) & 3)) * 8;

    const half_t* Ab = A + zb * sA + (long)m0 * lda + zs * K;
    const half_t* Bb = Bt + zb * sB + (long)n0 * ldb + zs * K;
    const long a0 = (long)r0 * lda + g0, a1 = (long)r1 * lda + g1;
    const long b0 = (long)r0 * ldb + g0, b1 = (long)r1 * ldb + g1;

    // fragment ds_read: row bits 1..2 come from l15 (bases are 16-aligned)
    const int qq = (q ^ ((l15 >> 1) & 3)) * 8; // halfs

    f32x4 acc[8][4] = {};
    const int nk2 = K >> 6;

#define STAGE_A(tt, ks) do { const int kb_ = (tt) * 64 + (ks) * 32; \
        gload_lds16(Ab + a0 + kb_, &As[(tt) & 1][ks][c0 * 8]);      \
        gload_lds16(Ab + a1 + kb_, &As[(tt) & 1][ks][c1 * 8]); } while (0)
#define STAGE_B(tt, ks) do { const int kb_ = (tt) * 64 + (ks) * 32; \
        gload_lds16(Bb + b0 + kb_, &Bs[(tt) & 1][ks][c0 * 8]);      \
        gload_lds16(Bb + b1 + kb_, &Bs[(tt) & 1][ks][c1 * 8]); } while (0)
#define LDB4(ksb) _Pragma("unroll") \
    for (int j = 0; j < 4; j++)     \
        bf[j] = *(const half8*)&Bs[cur][ksb][(wn * 64 + j * 16 + l15) * 32 + qq];
#define LDA4(ksb, mh) _Pragma("unroll") \
    for (int i = 0; i < 4; i++)         \
        af[i] = *(const half8*)&As[cur][ksb][(wm * 128 + (mh) * 64 + i * 16 + l15) * 32 + qq];
#define MFMA16(ar) _Pragma("unroll")                    \
    for (int i = 0; i < 4; i++) _Pragma("unroll")       \
        for (int j = 0; j < 4; j++)                     \
            acc[(ar) + i][j] = __builtin_amdgcn_mfma_f32_16x16x32_f16(af[i], bf[j], acc[(ar) + i][j], 0, 0, 0);

    // prologue: tile0 fully + tile1 h0(A-ks0),h1(B-ks0),h3(B-ks1); tile1 h2 is
    // issued in tile0's P1. vmcnt(6): tile0's 8 loads retired, tile1's 3
    // half-tiles in flight (steady-state invariant).
    STAGE_A(0, 0); STAGE_B(0, 0); STAGE_A(0, 1); STAGE_B(0, 1);
    if (nk2 > 1) {
        STAGE_A(1, 0); STAGE_B(1, 0); STAGE_B(1, 1);
        asm volatile("s_waitcnt vmcnt(6)" ::: "memory");
    } else {
        asm volatile("s_waitcnt vmcnt(0)" ::: "memory");
    }
    wgbar();

    for (int tt = 0; tt < nk2; ++tt) {
        const int cur = tt & 1;
        half8 af[4], bf[4];
        // ---- P1: ks=0, mh=0. Stage (tt+1) A-ks1 -> other buf (its tt-1 reads
        // finished before this tile started).
        LDB4(0); LDA4(0, 0);
        if (tt + 1 < nk2) STAGE_A(tt + 1, 1);
        wgbar();
        __builtin_amdgcn_s_setprio(1); MFMA16(0); __builtin_amdgcn_s_setprio(0);
        wgbar();
        // ---- P2: ks=0, mh=1 (bf reused). Stage (tt+2) B-ks0 -> this buf
        // (B-ks0 only read in P1; P1-end barrier passed).
        LDA4(0, 1);
        if (tt + 2 < nk2) STAGE_B(tt + 2, 0);
        wgbar();
        __builtin_amdgcn_s_setprio(1); MFMA16(4); __builtin_amdgcn_s_setprio(0);
        wgbar();
        // ---- P3: ks=1, mh=0. Stage (tt+2) A-ks0 -> this buf (A-ks0 read in
        // P1/P2 only).
        LDB4(1); LDA4(1, 0);
        if (tt + 2 < nk2) STAGE_A(tt + 2, 0);
        wgbar();
        __builtin_amdgcn_s_setprio(1); MFMA16(0); __builtin_amdgcn_s_setprio(0);
        wgbar();
        // ---- P4: ks=1, mh=1. Stage (tt+2) B-ks1 -> this buf (B-ks1 read in
        // P3 only). Then the once-per-K-tile counted wait: all but the newest
        // 3 half-tiles (P2/P3/P4 stages) retired => tile tt+1 fully in LDS.
        LDA4(1, 1);
        if (tt + 2 < nk2) STAGE_B(tt + 2, 1);
        wgbar();
        __builtin_amdgcn_s_setprio(1); MFMA16(4); __builtin_amdgcn_s_setprio(0);
        if (tt + 2 < nk2) asm volatile("s_waitcnt vmcnt(6)" ::: "memory");
        else              asm volatile("s_waitcnt vmcnt(0)" ::: "memory");
        wgbar();
    }
#undef STAGE_A
#undef STAGE_B
#undef LDB4
#undef LDA4
#undef MFMA16

    // epilogue: acc[a][j], a = mh*4+i -> row = wm*128 + mh*64 + i*16 + q*4 + r
    if (EPI == 1) {
        half_t* C = (half_t*)Cv + (long)blockIdx.z * sC + (long)m0 * ldc + n0;
#pragma unroll
        for (int a = 0; a < 8; a++) {
            const int rowb = wm * 128 + (a >> 2) * 64 + (a & 3) * 16 + q * 4;
#pragma unroll
            for (int j = 0; j < 4; j++) {
                const int col = wn * 64 + j * 16 + l15;
#pragma unroll
                for (int r = 0; r < 4; r++)
                    C[(long)(rowb + r) * ldc + col] = (half_t)(acc[a][j][r] * scale);
            }
        }
    } else {
        float* C = (float*)Cv + (long)blockIdx.z * sC + (long)m0 * ldc + n0;
#pragma unroll
        for (int a = 0; a < 8; a++) {
            const int rowb = wm * 128 + (a >> 2) * 64 + (a & 3) * 16 + q * 4;
#pragma unroll
            for (int j = 0; j < 4; j++) {
                const int col = wn * 64 + j * 16 + l15;
                const float bv = (EPI == 2) ? bias[n0 + col] : 0.0f;
#pragma unroll
                for (int r = 0; r < 4; r++)
                    C[(long)(rowb + r) * ldc + col] = acc[a][j][r] * scale + bv;
            }
        }
    }
}

// ---------------------------------------------------------------------------
// sum 4 split-K f16 partials (fp32 math) -> f16. P laid [z = b*4+s][1M halfs].
// Works for any output of size G*1M halfs (grid = G*512 blocks); for a 1M-half
// output (grid 512) b stays 0 and it just sums 4 consecutive 1M slabs.
__global__ __launch_bounds__(256) void ctx_reduce_h(
    const half_t* __restrict__ P, half_t* __restrict__ ctx)
{
    const long i = ((long)blockIdx.x * 256 + threadIdx.x) * 8;
    const long b = i >> 20;
    const long idx = i & ((1L << 20) - 1);
    const half_t* p = P + (b * 4) * (1L << 20) + idx;
    const half8 s0 = *(const half8*)(p);
    const half8 s1 = *(const half8*)(p + (1L << 20));
    const half8 s2 = *(const half8*)(p + 2 * (1L << 20));
    const half8 s3 = *(const half8*)(p + 3 * (1L << 20));
    half8 o;
#pragma unroll
    for (int j = 0; j < 8; j++)
        o[j] = (half_t)((float)s0[j] + (float)s1[j] + (float)s2[j] + (float)s3[j]);
    *(half8*)(ctx + i) = o;
}

// ---------------------------------------------------------------------------
// fp32 -> f16 elementwise (8 elems/thread)
__global__ __launch_bounds__(256) void convert_f32_f16(
    const float* __restrict__ in, half_t* __restrict__ out)
{
    const long i = ((long)blockIdx.x * 256 + threadIdx.x) * 8;
    const float4 a = *(const float4*)(in + i);
    const float4 b = *(const float4*)(in + i + 4);
    half8 o = {(half_t)a.x, (half_t)a.y, (half_t)a.z, (half_t)a.w,
               (half_t)b.x, (half_t)b.y, (half_t)b.z, (half_t)b.w};
    *(half8*)(out + i) = o;
}

// ---------------------------------------------------------------------------
// four 1024x1024 fp32 -> f16 transposed in one launch (z selects matrix)
__global__ void transpose_w4(const float* __restrict__ W0, const float* __restrict__ W1,
                             const float* __restrict__ W2, const float* __restrict__ W3,
                             half_t* __restrict__ Wt)
{
    __shared__ float tile[32][33];
    const float* W = blockIdx.z == 0 ? W0 : blockIdx.z == 1 ? W1
                   : blockIdx.z == 2 ? W2 : W3;
    half_t* dst = Wt + (size_t)blockIdx.z * 1024 * 1024;
    const int tx = threadIdx.x, ty = threadIdx.y;
    const int bx = blockIdx.x * 32, by = blockIdx.y * 32;
#pragma unroll
    for (int yy = ty; yy < 32; yy += 8)
        tile[yy][tx] = W[(long)(by + yy) * 1024 + bx + tx];
    __syncthreads();
#pragma unroll
    for (int yy = ty; yy < 32; yy += 8)
        dst[(long)(bx + yy) * 1024 + by + tx] = (half_t)tile[tx][yy];
}

// ---------------------------------------------------------------------------
// row softmax over 1024 features (f16 in, fp32 math); one block per row.
// Output scaled by 64 (f16 subnormal guard; compensated in final epilogue).
__global__ __launch_bounds__(256) void softmax_rows(
    const half_t* __restrict__ L, half_t* __restrict__ Qh)
{
    const int r = blockIdx.x;
    const int t = threadIdx.x;
    const half4 xh = ((const half4*)(L + (long)r * 1024))[t];
    const float x0 = (float)xh[0], x1 = (float)xh[1],
                x2 = (float)xh[2], x3 = (float)xh[3];
    float m = fmaxf(fmaxf(x0, x1), fmaxf(x2, x3));
#pragma unroll
    for (int o = 32; o > 0; o >>= 1) m = fmaxf(m, __shfl_xor(m, o, 64));
    __shared__ float redm[4], reds[4];
    const int wave = t >> 6;
    if ((t & 63) == 0) redm[wave] = m;
    __syncthreads();
    m = fmaxf(fmaxf(redm[0], redm[1]), fmaxf(redm[2], redm[3]));
    const float e0 = __expf(x0 - m), e1 = __expf(x1 - m),
                e2 = __expf(x2 - m), e3 = __expf(x3 - m);
    float s = e0 + e1 + e2 + e3;
#pragma unroll
    for (int o = 32; o > 0; o >>= 1) s += __shfl_xor(s, o, 64);
    if ((t & 63) == 0) reds[wave] = s;
    __syncthreads();
    s = reds[0] + reds[1] + reds[2] + reds[3];
    const float rs = 64.0f / s;
    half4 o4 = {(half_t)(e0 * rs), (half_t)(e1 * rs),
                (half_t)(e2 * rs), (half_t)(e3 * rs)};
    ((half4*)(Qh + (long)r * 1024))[t] = o4;
}

// ---------------------------------------------------------------------------
// row softmax over 4096 (sequence softmax in transposed layout); input rows
// live inside the merged KV-logit tensor [B][2048][4096] (K part = rows
// 0..1023 of each batch slab). One block per (b,d) row, 16 elems/thread.
// Output scaled by 64 into Kt [B][D][N].
__global__ __launch_bounds__(256) void softmax_seq(
    const half_t* __restrict__ KV, half_t* __restrict__ O)
{
    const long r = blockIdx.x;              // 0 .. B*D-1
    const long b = r >> 10;
    const long d = r & 1023;
    const int t = threadIdx.x;
    const half_t* row = KV + (b * 2048 + d) * 4096;
    const half8 h0 = *(const half8*)(row + t * 16);
    const half8 h1 = *(const half8*)(row + t * 16 + 8);
    float v[16];
#pragma unroll
    for (int j = 0; j < 8; j++) { v[j] = (float)h0[j]; v[8 + j] = (float)h1[j]; }
    float m = v[0];
#pragma unroll
    for (int j = 1; j < 16; j++) m = fmaxf(m, v[j]);
#pragma unroll
    for (int o = 32; o > 0; o >>= 1) m = fmaxf(m, __shfl_xor(m, o, 64));
    __shared__ float redm[4], reds[4];
    const int wave = t >> 6;
    if ((t & 63) == 0) redm[wave] = m;
    __syncthreads();
    m = fmaxf(fmaxf(redm[0], redm[1]), fmaxf(redm[2], redm[3]));
    float s = 0.0f;
#pragma unroll
    for (int j = 0; j < 16; j++) { v[j] = __expf(v[j] - m); s += v[j]; }
#pragma unroll
    for (int o = 32; o > 0; o >>= 1) s += __shfl_xor(s, o, 64);
    if ((t & 63) == 0) reds[wave] = s;
    __syncthreads();
    s = reds[0] + reds[1] + reds[2] + reds[3];
    const float rs = 64.0f / s;
    half8 o0, o1;
#pragma unroll
    for (int j = 0; j < 8; j++) {
        o0[j] = (half_t)(v[j] * rs);
        o1[j] = (half_t)(v[8 + j] * rs);
    }
    *(half8*)(O + r * 4096 + t * 16) = o0;
    *(half8*)(O + r * 4096 + t * 16 + 8) = o1;
}

// ---------------------------------------------------------------------------
extern "C" void kernel_launch(void* const* d_in, const int* in_sizes, int n_in,
                              void* d_out, int out_size, void* d_ws, size_t ws_size,
                              hipStream_t stream)
{
    const float* x  = (const float*)d_in[0];
    const float* Wq = (const float*)d_in[1];
    const float* Wk = (const float*)d_in[2];
    const float* Wv = (const float*)d_in[3];
    const float* Wo = (const float*)d_in[4];
    const float* bo = (const float*)d_in[5];
    float* out = (float*)d_out;

    // Workspace (184 MiB):
    //   Xh 32 MiB (x as f16; dead after KV GEMM -> reused for split-K partials P)
    //   KVreg 64 MiB: first 32 MiB doubles as Q-logits (dead before KV GEMM
    //     writes); then merged K|V'' logits [B][2048][4096] (K rows 0..1023,
    //     V'' = X*(Wv*Wo) rows 1024..2047 per batch slab, already transposed).
    char* w = (char*)d_ws;
    half_t* Xh  = (half_t*)w;                                  // 32 MiB
    half_t* P   = (half_t*)w;                                  // 32 MiB (aliases Xh)
    w += (size_t)R_ * D_ * 2;
    half_t* KVreg = (half_t*)w;                                // 64 MiB
    half_t* Qlog  = KVreg;                                     // 32 MiB (pre-KV)
    w += (size_t)B_ * 2048 * 4096 * 2;
    half_t* Qh  = (half_t*)w; w += (size_t)R_ * D_ * 2;        // 32 MiB (q * 64)
    half_t* Kt  = (half_t*)w; w += (size_t)R_ * D_ * 2;        // 32 MiB [B,D,N] (k * 64)
    half_t* Pw  = Kt;                                          // 8 MiB scratch (pre-softmax_seq)
    half_t* Wt  = (half_t*)w; w += (size_t)4 * D_ * D_ * 2;    // 8 MiB (Wq^T|Wk^T|Wvo^T|Wo^T)
    half_t* ctxT = (half_t*)w; w += (size_t)B_ * D_ * D_ * 2;  // 8 MiB (64 * (K^T V'')^T)
    half_t* Wvh = (half_t*)w; w += (size_t)B_ * D_ * D_ * 2;   // 2 MiB used (Wv as f16)
    (void)ws_size; (void)in_sizes; (void)n_in; (void)out_size;

    const dim3 blk(256);
    const dim3 blkg(512);
    const long M1 = 1L << 20;

    convert_f32_f16<<<R_ * D_ / (256 * 8), blk, 0, stream>>>(x, Xh);
    convert_f32_f16<<<512, blk, 0, stream>>>(Wv, Wvh);
    transpose_w4<<<dim3(32, 32, 4), dim3(32, 8), 0, stream>>>(Wq, Wk, Wv, Wo, Wt);

    // ---- Wvo^T[o][k] = sum_e Wo^T[o,e] * Wv[k,e]  (fold Wo into the V path:
    // out = q*(ctx*Wo) = q*(K^T*(X*(Wv*Wo)))). Split-K=4 over e, f16 partials
    // into Pw (Kt region, free until softmax_seq), reduce into Wt slot 2
    // (overwrites the unused Wv^T).
    gemm256<1, 2, 1><<<dim3(4, 4, 4), blkg, 0, stream>>>(Wt + 3 * M1, Wvh, Pw, nullptr,
        1024, 1024, 1024, 256, 0, 0, M1, 1.0f);
    ctx_reduce_h<<<512, blk, 0, stream>>>(Pw, Wt + 2 * M1);

    // ---- Q: Qlog[n,d] = Xh @ Wq (A big -> SWAP=1), then feature softmax
    gemm256<1, 0, 1><<<dim3(64, 4, 1), blkg, 0, stream>>>(Xh, Wt, Qlog, nullptr,
        1024, 1024, 1024, 1024, 0, 0, 0, 1.0f);
    softmax_rows<<<R_, blk, 0, stream>>>(Qlog, Qh);

    // ---- merged K|V'' transposed: KVreg[b][m][n] = sum_k A[m,k] Xh[b][n,k]
    // with A rows = Wk^T (m 0..1023, K logits) | Wvo^T (m 1024..2047, V'').
    gemm256<1, 0, 0><<<dim3(16, 8, B_), blkg, 0, stream>>>(Wt + M1, Xh, KVreg, nullptr,
        1024, 1024, 4096, 1024, 0, (long)N_ * D_, (long)2048 * 4096, 1.0f);
    softmax_seq<<<B_ * D_, blk, 0, stream>>>(KVreg, Kt);

    // ---- ctxT[b][o][d] = sum_n v''[n,o] * (64 k[n,d])  (A = V''t slab,
    // Bt = Kt; both [.][n] layout). Split-K=4 over n, f16 partials in P
    // (Xh dead), reduce -> ctxT. Produces the TRANSPOSED context the final
    // GEMM consumes directly (Mt GEMM + its reduce eliminated).
    gemm256<1, 2, 1><<<dim3(4, 4, 16), blkg, 0, stream>>>(KVreg + (long)1024 * 4096, Kt, P, nullptr,
        4096, 4096, 1024, N_ / 4,
        (long)2048 * 4096, (long)D_ * N_, M1, 1.0f);
    ctx_reduce_h<<<2048, blk, 0, stream>>>(P, ctxT);

    // ---- out[b][n][o] = (sum_d 64 q[n,d] * ctxT[b][o][d]) * 2^-25 + bo[o]
    // 2^-25 = (1/8 head scale) * (1/1024 D_OUT) * (1/64 q) * (1/64 k), all exact
    gemm256<2, 0, 1><<<dim3(16, 4, B_), blkg, 0, stream>>>(Qh, ctxT, out, bo,
        1024, 1024, 1024, 1024,
        (long)N_ * D_, M1, (long)N_ * D_,
        1.0f / 33554432.0f);
}

// Round 4
// 364.671 us; speedup vs baseline: 1.1519x; 1.0630x over previous
//
#include <hip/hip_runtime.h>

typedef _Float16 half_t;
typedef __attribute__((ext_vector_type(8))) _Float16 half8;
typedef __attribute__((ext_vector_type(4))) _Float16 half4;
typedef __attribute__((ext_vector_type(4))) float f32x4;

#define B_ 4
#define N_ 4096
#define D_ 1024
#define R_ (B_ * N_) // 16384

// ---------------------------------------------------------------------------
// async global->LDS, 16B per lane. LDS dest must be wave-uniform base + lane*16.
__device__ __forceinline__ void gload_lds16(const half_t* g, half_t* l) {
    __builtin_amdgcn_global_load_lds(
        (const __attribute__((address_space(1))) unsigned int*)g,
        (__attribute__((address_space(3))) unsigned int*)l, 16, 0, 0);
}

// raw workgroup barrier: NO vmcnt(0)/lgkmcnt(0) drain (that drain is the
// 2-phase ceiling). Memory clobbers pin compile-time order of LDS/global ops
// to their phase. Cross-wave visibility of global_load_lds writes is carried
// by the explicit counted vmcnt before the barrier.
__device__ __forceinline__ void wgbar() {
    asm volatile("" ::: "memory");
    __builtin_amdgcn_s_barrier();
    asm volatile("" ::: "memory");
}

// ---------------------------------------------------------------------------
// C[m,n] = sum_k A[m,k] * Bt[n,k]   (A row-major [M,K], B given transposed [N,K])
// 256x256 tile, BK=64, 512 threads (8 waves = 2M x 4N, each 128x64 output).
// 8-phase schedule (4 phases per K-tile, 2 K-tiles per LDS double-buffer pair):
//   phase = { ds-read frags | issue 1 half-tile global_load_lds } barrier
//           { setprio(1) 16x MFMA setprio(0) } barrier
// Counted vmcnt(6) once per K-tile (3 half-tiles in flight), drain only in tail.
// LDS per ks-block: [256 rows][32 k] halfs (64B rows), 16B chunks XOR-swizzled:
//   phys_chunk(row,q) = row*4 + (q ^ ((row>>1)&3))
// applied on BOTH sides: pre-swizzled global source (stage) + swizzled ds_read.
// EPI: 0 = fp32 C, 1 = f16 C, 2 = fp32 C + bias (bias indexed by column)
// ZSHIFT: blockIdx.z = (batch << ZSHIFT) | ksplit; k window = ksplit*K .. +K.
//         C offset uses full blockIdx.z (split-K partials laid out per z).
// Requires: K % 64 == 0, nk2 = K/64 >= 2.
template <int EPI, int ZSHIFT, int SWAP>
__global__ __launch_bounds__(512, 2) void gemm256(
    const half_t* __restrict__ A, const half_t* __restrict__ Bt,
    void* __restrict__ Cv, const float* __restrict__ bias,
    int lda, int ldb, int ldc, int K,
    long sA, long sB, long sC, float scale)
{
    __shared__ __align__(16) half_t As[2][2][256 * 32]; // [buf][ks][row*32+chunk]
    __shared__ __align__(16) half_t Bs[2][2][256 * 32];

    const int t = threadIdx.x;
    const int wave = t >> 6;
    const int lane = t & 63;
    const int l15 = lane & 15;
    const int q = lane >> 4;
    const int wm = wave >> 2;  // 0..1 (M)
    const int wn = wave & 3;   // 0..3 (N)
    const int m0 = (SWAP ? blockIdx.x : blockIdx.y) * 256;
    const int n0 = (SWAP ? blockIdx.y : blockIdx.x) * 256;
    const long zb = blockIdx.z >> ZSHIFT;
    const int zs = blockIdx.z & ((1 << ZSHIFT) - 1);

    // staging: physical chunk c (16B) holds logical (row = c>>2, chunk = (c&3)^((c>>3)&3))
    const int c0 = t, c1 = t + 512;
    const int r0 = c0 >> 2, r1 = c1 >> 2;
    const int g0 = ((c0 & 3) ^ ((c0 >> 3) & 3)) * 8; // halfs
    const int g1 = ((c1 & 3) ^ ((c1 >> 3) & 3)) * 8;

    const half_t* Ab = A + zb * sA + (long)m0 * lda + zs * K;
    const half_t* Bb = Bt + zb * sB + (long)n0 * ldb + zs * K;
    const long a0 = (long)r0 * lda + g0, a1 = (long)r1 * lda + g1;
    const long b0 = (long)r0 * ldb + g0, b1 = (long)r1 * ldb + g1;

    // fragment ds_read: row bits 1..2 come from l15 (bases are 16-aligned)
    const int qq = (q ^ ((l15 >> 1) & 3)) * 8; // halfs

    f32x4 acc[8][4] = {};
    const int nk2 = K >> 6;

#define STAGE_A(tt, ks) do { const int kb_ = (tt) * 64 + (ks) * 32; \
        gload_lds16(Ab + a0 + kb_, &As[(tt) & 1][ks][c0 * 8]);      \
        gload_lds16(Ab + a1 + kb_, &As[(tt) & 1][ks][c1 * 8]); } while (0)
#define STAGE_B(tt, ks) do { const int kb_ = (tt) * 64 + (ks) * 32; \
        gload_lds16(Bb + b0 + kb_, &Bs[(tt) & 1][ks][c0 * 8]);      \
        gload_lds16(Bb + b1 + kb_, &Bs[(tt) & 1][ks][c1 * 8]); } while (0)
#define LDB4(ksb) _Pragma("unroll") \
    for (int j = 0; j < 4; j++)     \
        bf[j] = *(const half8*)&Bs[cur][ksb][(wn * 64 + j * 16 + l15) * 32 + qq];
#define LDA4(ksb, mh) _Pragma("unroll") \
    for (int i = 0; i < 4; i++)         \
        af[i] = *(const half8*)&As[cur][ksb][(wm * 128 + (mh) * 64 + i * 16 + l15) * 32 + qq];
#define MFMA16(ar) _Pragma("unroll")                    \
    for (int i = 0; i < 4; i++) _Pragma("unroll")       \
        for (int j = 0; j < 4; j++)                     \
            acc[(ar) + i][j] = __builtin_amdgcn_mfma_f32_16x16x32_f16(af[i], bf[j], acc[(ar) + i][j], 0, 0, 0);

    // prologue: tile0 fully + tile1 h0(A-ks0),h1(B-ks0),h3(B-ks1); tile1 h2 is
    // issued in tile0's P1. vmcnt(6): tile0's 8 loads retired, tile1's 3
    // half-tiles in flight (steady-state invariant).
    STAGE_A(0, 0); STAGE_B(0, 0); STAGE_A(0, 1); STAGE_B(0, 1);
    if (nk2 > 1) {
        STAGE_A(1, 0); STAGE_B(1, 0); STAGE_B(1, 1);
        asm volatile("s_waitcnt vmcnt(6)" ::: "memory");
    } else {
        asm volatile("s_waitcnt vmcnt(0)" ::: "memory");
    }
    wgbar();

    for (int tt = 0; tt < nk2; ++tt) {
        const int cur = tt & 1;
        half8 af[4], bf[4];
        // ---- P1: ks=0, mh=0. Stage (tt+1) A-ks1 -> other buf (its tt-1 reads
        // finished before this tile started).
        LDB4(0); LDA4(0, 0);
        if (tt + 1 < nk2) STAGE_A(tt + 1, 1);
        wgbar();
        __builtin_amdgcn_s_setprio(1); MFMA16(0); __builtin_amdgcn_s_setprio(0);
        wgbar();
        // ---- P2: ks=0, mh=1 (bf reused). Stage (tt+2) B-ks0 -> this buf
        // (B-ks0 only read in P1; P1-end barrier passed).
        LDA4(0, 1);
        if (tt + 2 < nk2) STAGE_B(tt + 2, 0);
        wgbar();
        __builtin_amdgcn_s_setprio(1); MFMA16(4); __builtin_amdgcn_s_setprio(0);
        wgbar();
        // ---- P3: ks=1, mh=0. Stage (tt+2) A-ks0 -> this buf (A-ks0 read in
        // P1/P2 only).
        LDB4(1); LDA4(1, 0);
        if (tt + 2 < nk2) STAGE_A(tt + 2, 0);
        wgbar();
        __builtin_amdgcn_s_setprio(1); MFMA16(0); __builtin_amdgcn_s_setprio(0);
        wgbar();
        // ---- P4: ks=1, mh=1. Stage (tt+2) B-ks1 -> this buf (B-ks1 read in
        // P3 only). Then the once-per-K-tile counted wait: all but the newest
        // 3 half-tiles (P2/P3/P4 stages) retired => tile tt+1 fully in LDS.
        LDA4(1, 1);
        if (tt + 2 < nk2) STAGE_B(tt + 2, 1);
        wgbar();
        __builtin_amdgcn_s_setprio(1); MFMA16(4); __builtin_amdgcn_s_setprio(0);
        if (tt + 2 < nk2) asm volatile("s_waitcnt vmcnt(6)" ::: "memory");
        else              asm volatile("s_waitcnt vmcnt(0)" ::: "memory");
        wgbar();
    }
#undef STAGE_A
#undef STAGE_B
#undef LDB4
#undef LDA4
#undef MFMA16

    // epilogue: acc[a][j], a = mh*4+i -> row = wm*128 + mh*64 + i*16 + q*4 + r
    if (EPI == 1) {
        half_t* C = (half_t*)Cv + (long)blockIdx.z * sC + (long)m0 * ldc + n0;
#pragma unroll
        for (int a = 0; a < 8; a++) {
            const int rowb = wm * 128 + (a >> 2) * 64 + (a & 3) * 16 + q * 4;
#pragma unroll
            for (int j = 0; j < 4; j++) {
                const int col = wn * 64 + j * 16 + l15;
#pragma unroll
                for (int r = 0; r < 4; r++)
                    C[(long)(rowb + r) * ldc + col] = (half_t)(acc[a][j][r] * scale);
            }
        }
    } else {
        float* C = (float*)Cv + (long)blockIdx.z * sC + (long)m0 * ldc + n0;
#pragma unroll
        for (int a = 0; a < 8; a++) {
            const int rowb = wm * 128 + (a >> 2) * 64 + (a & 3) * 16 + q * 4;
#pragma unroll
            for (int j = 0; j < 4; j++) {
                const int col = wn * 64 + j * 16 + l15;
                const float bv = (EPI == 2) ? bias[n0 + col] : 0.0f;
#pragma unroll
                for (int r = 0; r < 4; r++)
                    C[(long)(rowb + r) * ldc + col] = acc[a][j][r] * scale + bv;
            }
        }
    }
}

// ---------------------------------------------------------------------------
// sum 4 split-K f16 partials (fp32 math) -> f16. P laid [z = b*4+s][1M halfs].
// Works for any output of size G*1M halfs (grid = G*512 blocks).
__global__ __launch_bounds__(256) void ctx_reduce_h(
    const half_t* __restrict__ P, half_t* __restrict__ ctx)
{
    const long i = ((long)blockIdx.x * 256 + threadIdx.x) * 8;
    const long b = i >> 20;
    const long idx = i & ((1L << 20) - 1);
    const half_t* p = P + (b * 4) * (1L << 20) + idx;
    const half8 s0 = *(const half8*)(p);
    const half8 s1 = *(const half8*)(p + (1L << 20));
    const half8 s2 = *(const half8*)(p + 2 * (1L << 20));
    const half8 s3 = *(const half8*)(p + 3 * (1L << 20));
    half8 o;
#pragma unroll
    for (int j = 0; j < 8; j++)
        o[j] = (half_t)((float)s0[j] + (float)s1[j] + (float)s2[j] + (float)s3[j]);
    *(half8*)(ctx + i) = o;
}

// ---------------------------------------------------------------------------
// Fused preparation, one dispatch, 256-thread blocks:
//   bid <  4096         : transpose 32x32 f32 tile of W{q,k,v,o} -> f16 into Wt
//   4096 <= bid < 4608  : Wv fp32 -> f16 straight copy (Wvh)
//   4608 <= bid < 12800 : x fp32 -> f16 (Xh), 2048 elems per block
__global__ __launch_bounds__(256) void prep_fused(
    const float* __restrict__ x,
    const float* __restrict__ W0, const float* __restrict__ W1,
    const float* __restrict__ W2, const float* __restrict__ W3,
    half_t* __restrict__ Wt, half_t* __restrict__ Wvh, half_t* __restrict__ Xh)
{
    const int bid = blockIdx.x;
    const int t = threadIdx.x;
    if (bid < 4096) {
        __shared__ float tile[32][33];
        const int z = bid >> 10;
        const int rem = bid & 1023;
        const int by = (rem >> 5) * 32, bx = (rem & 31) * 32;
        const float* W = z == 0 ? W0 : z == 1 ? W1 : z == 2 ? W2 : W3;
        half_t* dst = Wt + (size_t)z * 1024 * 1024;
        const int tx = t & 31, ty = t >> 5; // 32 x 8
#pragma unroll
        for (int yy = ty; yy < 32; yy += 8)
            tile[yy][tx] = W[(long)(by + yy) * 1024 + bx + tx];
        __syncthreads();
#pragma unroll
        for (int yy = ty; yy < 32; yy += 8)
            dst[(long)(bx + yy) * 1024 + by + tx] = (half_t)tile[tx][yy];
    } else if (bid < 4608) {
        const long i = ((long)(bid - 4096) * 256 + t) * 8;
        const float4 a = *(const float4*)(W2 + i);
        const float4 b = *(const float4*)(W2 + i + 4);
        half8 o = {(half_t)a.x, (half_t)a.y, (half_t)a.z, (half_t)a.w,
                   (half_t)b.x, (half_t)b.y, (half_t)b.z, (half_t)b.w};
        *(half8*)(Wvh + i) = o;
    } else {
        const long i = ((long)(bid - 4608) * 256 + t) * 8;
        const float4 a = *(const float4*)(x + i);
        const float4 b = *(const float4*)(x + i + 4);
        half8 o = {(half_t)a.x, (half_t)a.y, (half_t)a.z, (half_t)a.w,
                   (half_t)b.x, (half_t)b.y, (half_t)b.z, (half_t)b.w};
        *(half8*)(Xh + i) = o;
    }
}

// ---------------------------------------------------------------------------
// Fused softmax dispatch (both softmaxes, launched after both logits GEMMs):
//   bid < 4096 : sequence softmax over 4096 for row (b,d) of the K-logit part
//                of KVreg [B][2048][4096]; 256 thr, 16 elems/thr; out *64 -> Kt.
//   bid >= 4096: feature softmax over 1024, ONE WAVE PER ROW (4 rows/block),
//                no LDS, no barriers; out *64 -> Qh.
__global__ __launch_bounds__(256) void softmax_fused(
    const half_t* __restrict__ KV, half_t* __restrict__ Kt,
    const half_t* __restrict__ Qlog, half_t* __restrict__ Qh)
{
    const int bid = blockIdx.x;
    const int t = threadIdx.x;
    if (bid < B_ * D_) {
        const long r = bid;
        const long b = r >> 10;
        const long d = r & 1023;
        const half_t* row = KV + (b * 2048 + d) * 4096;
        const half8 h0 = *(const half8*)(row + t * 16);
        const half8 h1 = *(const half8*)(row + t * 16 + 8);
        float v[16];
#pragma unroll
        for (int j = 0; j < 8; j++) { v[j] = (float)h0[j]; v[8 + j] = (float)h1[j]; }
        float m = v[0];
#pragma unroll
        for (int j = 1; j < 16; j++) m = fmaxf(m, v[j]);
#pragma unroll
        for (int o = 32; o > 0; o >>= 1) m = fmaxf(m, __shfl_xor(m, o, 64));
        __shared__ float redm[4], reds[4];
        const int wave = t >> 6;
        if ((t & 63) == 0) redm[wave] = m;
        __syncthreads();
        m = fmaxf(fmaxf(redm[0], redm[1]), fmaxf(redm[2], redm[3]));
        float s = 0.0f;
#pragma unroll
        for (int j = 0; j < 16; j++) { v[j] = __expf(v[j] - m); s += v[j]; }
#pragma unroll
        for (int o = 32; o > 0; o >>= 1) s += __shfl_xor(s, o, 64);
        if ((t & 63) == 0) reds[wave] = s;
        __syncthreads();
        s = reds[0] + reds[1] + reds[2] + reds[3];
        const float rs = 64.0f / s;
        half8 o0, o1;
#pragma unroll
        for (int j = 0; j < 8; j++) {
            o0[j] = (half_t)(v[j] * rs);
            o1[j] = (half_t)(v[8 + j] * rs);
        }
        *(half8*)(Kt + r * 4096 + t * 16) = o0;
        *(half8*)(Kt + r * 4096 + t * 16 + 8) = o1;
    } else {
        const long r = ((long)(bid - B_ * D_)) * 4 + (t >> 6);
        const int lane = t & 63;
        const half_t* row = Qlog + r * 1024 + lane * 16;
        const half8 h0 = *(const half8*)(row);
        const half8 h1 = *(const half8*)(row + 8);
        float v[16];
#pragma unroll
        for (int j = 0; j < 8; j++) { v[j] = (float)h0[j]; v[8 + j] = (float)h1[j]; }
        float m = v[0];
#pragma unroll
        for (int j = 1; j < 16; j++) m = fmaxf(m, v[j]);
#pragma unroll
        for (int o = 32; o > 0; o >>= 1) m = fmaxf(m, __shfl_xor(m, o, 64));
        float s = 0.0f;
#pragma unroll
        for (int j = 0; j < 16; j++) { v[j] = __expf(v[j] - m); s += v[j]; }
#pragma unroll
        for (int o = 32; o > 0; o >>= 1) s += __shfl_xor(s, o, 64);
        const float rs = 64.0f / s;
        half8 o0, o1;
#pragma unroll
        for (int j = 0; j < 8; j++) {
            o0[j] = (half_t)(v[j] * rs);
            o1[j] = (half_t)(v[8 + j] * rs);
        }
        half_t* orow = Qh + r * 1024 + lane * 16;
        *(half8*)(orow) = o0;
        *(half8*)(orow + 8) = o1;
    }
}

// ---------------------------------------------------------------------------
extern "C" void kernel_launch(void* const* d_in, const int* in_sizes, int n_in,
                              void* d_out, int out_size, void* d_ws, size_t ws_size,
                              hipStream_t stream)
{
    const float* x  = (const float*)d_in[0];
    const float* Wq = (const float*)d_in[1];
    const float* Wk = (const float*)d_in[2];
    const float* Wv = (const float*)d_in[3];
    const float* Wo = (const float*)d_in[4];
    const float* bo = (const float*)d_in[5];
    float* out = (float*)d_out;

    // Workspace (184 MiB):
    //   Xh 32 MiB (x as f16; dead after ctx GEMM inputs ready -> reused for P)
    //   KVreg 64 MiB: merged K|V'' logits [B][2048][4096]
    //     (K rows 0..1023, V'' = X*(Wv*Wo) rows 1024..2047, transposed layout)
    //   Q-logits live in d_out (64 MiB fp32 buffer, dead until final GEMM).
    char* w = (char*)d_ws;
    half_t* Xh  = (half_t*)w;                                  // 32 MiB
    half_t* P   = (half_t*)w;                                  // 32 MiB (aliases Xh)
    w += (size_t)R_ * D_ * 2;
    half_t* KVreg = (half_t*)w;                                // 64 MiB
    w += (size_t)B_ * 2048 * 4096 * 2;
    half_t* Qh  = (half_t*)w; w += (size_t)R_ * D_ * 2;        // 32 MiB (q * 64)
    half_t* Kt  = (half_t*)w; w += (size_t)R_ * D_ * 2;        // 32 MiB [B,D,N] (k * 64)
    half_t* Pw  = Kt;                                          // 8 MiB scratch (pre-softmax)
    half_t* Wt  = (half_t*)w; w += (size_t)4 * D_ * D_ * 2;    // 8 MiB (Wq^T|Wk^T|Wvo^T|Wo^T)
    half_t* ctxT = (half_t*)w; w += (size_t)B_ * D_ * D_ * 2;  // 8 MiB (64 * (K^T V'')^T)
    half_t* Wvh = (half_t*)w; w += (size_t)B_ * D_ * D_ * 2;   // 2 MiB used (Wv as f16)
    half_t* Qlog = (half_t*)out;                               // 32 MiB in d_out
    (void)ws_size; (void)in_sizes; (void)n_in; (void)out_size;

    const dim3 blk(256);
    const dim3 blkg(512);
    const long M1 = 1L << 20;

    // ---- all input conversions + weight transposes, one dispatch
    prep_fused<<<12800, blk, 0, stream>>>(x, Wq, Wk, Wv, Wo, Wt, Wvh, Xh);

    // ---- Wvo^T[o][k] = sum_e Wo^T[o,e] * Wv[k,e]  (fold Wo into the V path:
    // out = q*(ctx*Wo) = q*(K^T*(X*(Wv*Wo)))). Split-K=4 over e, f16 partials
    // into Pw (Kt region, free until softmax), reduce into Wt slot 2.
    gemm256<1, 2, 1><<<dim3(4, 4, 4), blkg, 0, stream>>>(Wt + 3 * M1, Wvh, Pw, nullptr,
        1024, 1024, 1024, 256, 0, 0, M1, 1.0f);
    ctx_reduce_h<<<512, blk, 0, stream>>>(Pw, Wt + 2 * M1);

    // ---- Q logits: Qlog[n,d] = Xh @ Wq (A big -> SWAP=1) -> d_out scratch
    gemm256<1, 0, 1><<<dim3(64, 4, 1), blkg, 0, stream>>>(Xh, Wt, Qlog, nullptr,
        1024, 1024, 1024, 1024, 0, 0, 0, 1.0f);

    // ---- merged K|V'' transposed: KVreg[b][m][n] = sum_k A[m,k] Xh[b][n,k]
    // with A rows = Wk^T (m 0..1023, K logits) | Wvo^T (m 1024..2047, V'').
    gemm256<1, 0, 0><<<dim3(16, 8, B_), blkg, 0, stream>>>(Wt + M1, Xh, KVreg, nullptr,
        1024, 1024, 4096, 1024, 0, (long)N_ * D_, (long)2048 * 4096, 1.0f);

    // ---- both softmaxes in one dispatch (seq part -> Kt, feature part -> Qh)
    softmax_fused<<<B_ * D_ + R_ / 4, blk, 0, stream>>>(KVreg, Kt, Qlog, Qh);

    // ---- ctxT[b][o][d] = sum_n v''[n,o] * (64 k[n,d])  (A = V''t slab,
    // Bt = Kt; both [.][n] layout). Split-K=4 over n, f16 partials in P
    // (Xh dead), reduce -> ctxT.
    gemm256<1, 2, 1><<<dim3(4, 4, 16), blkg, 0, stream>>>(KVreg + (long)1024 * 4096, Kt, P, nullptr,
        4096, 4096, 1024, N_ / 4,
        (long)2048 * 4096, (long)D_ * N_, M1, 1.0f);
    ctx_reduce_h<<<2048, blk, 0, stream>>>(P, ctxT);

    // ---- out[b][n][o] = (sum_d 64 q[n,d] * ctxT[b][o][d]) * 2^-25 + bo[o]
    // 2^-25 = (1/8 head scale) * (1/1024 D_OUT) * (1/64 q) * (1/64 k), all exact
    gemm256<2, 0, 1><<<dim3(16, 4, B_), blkg, 0, stream>>>(Qh, ctxT, out, bo,
        1024, 1024, 1024, 1024,
        (long)N_ * D_, M1, (long)N_ * D_,
        1.0f / 33554432.0f);
}